// Round 8
// baseline (319.515 us; speedup 1.0000x reference)
//
#include <hip/hip_runtime.h>
#include <hip/hip_bf16.h>
#include <cmath>

#define HDIM 2048
#define H4   (HDIM / 4)         // 512 float4 per row
#define NEXP 64
#define TTOT 16384
#define BKC  128                // k per staged chunk (R8: 2x bigger, half barriers)
#define NCHUNK (HDIM / BKC)     // 16 (full K in-block)
#define BTOK 32                 // tokens per block (grid 512 -> 2 blocks/CU)
#define NBLK (TTOT / BTOK)      // 512 blocks
#define LDT  136                // padded k-stride (shorts); rows 16B-aligned
#define LDS_SC 65

typedef unsigned short u16;
typedef short  bf16x8 __attribute__((ext_vector_type(8)));
typedef float  f32x16 __attribute__((ext_vector_type(16)));

// ws layout (floats):
// [0 .. 32767]       prob_part[512][64]
// [32768 .. 65535]   gate_part[512][64]
// [65536 ..]         gws: gw 3-level bf16 pre-split (196608 floats as shorts)
#define WS_AUX_FLOATS  (2 * NBLK * NEXP)                   // 65536
#define WS_GWS_OFF     WS_AUX_FLOATS
#define GWS_FLOATS     (3 * NEXP * HDIM / 2)               // 196608
#define WS_NEEDED_FLOATS (WS_GWS_OFF + GWS_FLOATS)
#define ESTR (NEXP * HDIM)      // shorts per gw level

// RNE pack of 2 fp32 -> 2 bf16 in one u32 (v_cvt_pk_bf16_f32); low16 = a.
__device__ __forceinline__ unsigned cvtpk(float a, float b) {
    __hip_bfloat162 h2 = __float22bfloat162_rn(make_float2(a, b));
    unsigned r;
    __builtin_memcpy(&r, &h2, sizeof(r));
    return r;
}
// split f4 -> h/m/l packed uint2 (RNE each level; residuals exact/Sterbenz)
__device__ __forceinline__ void split3(float4 f, uint2* H, uint2* M, uint2* L) {
    unsigned h0 = cvtpk(f.x, f.y), h1 = cvtpk(f.z, f.w);
    float r0 = f.x - __uint_as_float(h0 << 16);
    float r1 = f.y - __uint_as_float(h0 & 0xffff0000u);
    float r2 = f.z - __uint_as_float(h1 << 16);
    float r3 = f.w - __uint_as_float(h1 & 0xffff0000u);
    unsigned m0 = cvtpk(r0, r1), m1 = cvtpk(r2, r3);
    float s0 = r0 - __uint_as_float(m0 << 16);
    float s1 = r1 - __uint_as_float(m0 & 0xffff0000u);
    float s2 = r2 - __uint_as_float(m1 << 16);
    float s3 = r3 - __uint_as_float(m1 & 0xffff0000u);
    unsigned l0 = cvtpk(s0, s1), l1 = cvtpk(s2, s3);
    *H = make_uint2(h0, h1); *M = make_uint2(m0, m1); *L = make_uint2(l0, l1);
}

// ===========================================================================
// Kernel 0: one-time gw 3-way bf16 pre-split (512 KB; keeps the fused
// kernel's b-staging a pure L2 copy).
// ===========================================================================
__global__ __launch_bounds__(256) void split_gw_k(
    const float* __restrict__ gw, u16* __restrict__ gws)
{
    const int i = blockIdx.x * 256 + threadIdx.x;   // one float4 each; 32768 total
    float4 f = reinterpret_cast<const float4*>(gw)[i];
    uint2 h, m, l;
    split3(f, &h, &m, &l);
    reinterpret_cast<uint2*>(gws)[i]            = h;   // uint2 = 4 shorts
    reinterpret_cast<uint2*>(gws + ESTR)[i]     = m;
    reinterpret_cast<uint2*>(gws + 2 * ESTR)[i] = l;
}

// ===========================================================================
// Fused kernel v3: full-K MFMA GEMM (3-way bf16 split) + in-block epilogue.
// R7 post-mortem fixes: (1) BKC=128 -> 16 chunks (halves barrier count;
// R7's 32 chunks at ~const cost/chunk was the 101us); (2) next-chunk loads
// issued AFTER barrier-1, so their vmcnt(0) drain at barrier-2 is covered
// by the MFMA phase (R7 issued them before barrier-1 -> drained instantly,
// full HBM latency serialized per chunk -- the m97 s_barrier-drain lesson).
// Grid 512 x 256 thr, 2 blocks/CU (LDS 76.5 KB). 4 waves: wn = expert half,
// kh = K half of each chunk's 8 K=16 steps; kh-accs combine via score LDS.
// ===========================================================================
__global__ __launch_bounds__(256, 2) void router_fused3(
    const float* __restrict__ x,        // [T, H]
    const u16*   __restrict__ gws,      // [3][E][H] pre-split bf16
    const float* __restrict__ rep,
    const float* __restrict__ loads,
    const float* __restrict__ counts,
    const int*   __restrict__ total_dec,
    float* __restrict__ out_w,
    float* __restrict__ out_idx,
    float* __restrict__ prob_part,      // [512][64]
    float* __restrict__ gate_part)      // [512][64]
{
    // staging pool: aT[3][32][136] + bT[3][64][136] shorts = 76.5 KB.
    // sc_s[32][65] floats (8.3 KB) aliases the pool after the MFMA loop.
    __shared__ __align__(16) char pool[(3 * BTOK * LDT + 3 * NEXP * LDT) * sizeof(short)];
    short (*aT)[BTOK][LDT] = reinterpret_cast<short (*)[BTOK][LDT]>(pool);
    short (*bT)[NEXP][LDT] =
        reinterpret_cast<short (*)[NEXP][LDT]>(pool + 3 * BTOK * LDT * sizeof(short));
    float (*sc_s)[LDS_SC] = reinterpret_cast<float (*)[LDS_SC]>(pool);
    __shared__ float bias_s[NEXP];
    __shared__ float m_s[BTOK], zi_s[BTOK];
    __shared__ int   i1_s[BTOK], i2_s[BTOK];

    const int tid  = threadIdx.x;
    const int lane = tid & 63;
    const int l31  = lane & 31;
    const int lhi  = lane >> 5;         // K-half within fragment
    const int w    = tid >> 6;          // wave 0..3
    const int wn   = w & 1;             // expert half (32 cols)
    const int kh   = w >> 1;            // chunk K-half (ks 0..3 vs 4..7)
    const int rt   = blockIdx.x;        // token block 0..511
    const int T0   = rt * BTOK;

    if (tid < NEXP) {
        float L = logf((float)(*total_dec) + 1.0f);
        bias_s[tid] = 0.1f * rep[tid] - 0.1f * loads[tid]
                    + 0.1f * sqrtf(L / (counts[tid] + 1e-10f));
    }

    // x staging: 32 rows x 8 thr/row, 16 k (4 float4) each
    const int srow = tid >> 3;
    const int scol = tid & 7;
    // gw staging: 64 rows x 4 thr/row, 32 k (4 uint4 per level) each
    const int grow = tid >> 2;
    const int gcol = tid & 3;

    const float4* __restrict__ x4 = reinterpret_cast<const float4*>(x)
        + (size_t)(T0 + srow) * H4 + scol * 4;
    const u16* __restrict__ gwsB = gws + (size_t)grow * HDIM + gcol * 32;

    f32x16 acc;
    #pragma unroll
    for (int i = 0; i < 16; ++i) acc[i] = 0.0f;

    // fragment read pointers (chunk-invariant); rows 16B-aligned (LDT=136)
    const short* aP[3];
    const short* bP[3];
    #pragma unroll
    for (int v = 0; v < 3; ++v) {
        aP[v] = &aT[v][l31][8 * lhi];
        bP[v] = &bT[v][32 * wn + l31][8 * lhi];
    }

    float4 xa[4];       // x regs for the chunk being staged next
    uint4  bq[3][4];    // pre-split gw regs (pure L2 copy)

#define LOAD_X(CH) do {                                                        \
        _Pragma("unroll")                                                      \
        for (int j = 0; j < 4; ++j) xa[j] = x4[(CH) * (BKC / 4) + j];          \
    } while (0)
#define LOAD_B(CH) do {                                                        \
        _Pragma("unroll")                                                      \
        for (int v = 0; v < 3; ++v)                                            \
            _Pragma("unroll")                                                  \
            for (int j = 0; j < 4; ++j)                                        \
                bq[v][j] = *reinterpret_cast<const uint4*>(                    \
                    gwsB + (size_t)v * ESTR + (CH) * BKC + j * 8);             \
    } while (0)

    LOAD_X(0);
    LOAD_B(0);

    for (int ch = 0; ch < NCHUNK; ++ch) {
        // ---- staging phase: consume regs -> LDS (vmcnt waits here) ----
        #pragma unroll
        for (int jp = 0; jp < 2; ++jp) {   // pairs (0,1) and (2,3)
            uint2 h0, m0, l0, h1, m1, l1;
            split3(xa[2 * jp],     &h0, &m0, &l0);
            split3(xa[2 * jp + 1], &h1, &m1, &l1);
            const int kl = scol * 16 + jp * 8;
            *reinterpret_cast<uint4*>(&aT[0][srow][kl]) =
                make_uint4(h0.x, h0.y, h1.x, h1.y);
            *reinterpret_cast<uint4*>(&aT[1][srow][kl]) =
                make_uint4(m0.x, m0.y, m1.x, m1.y);
            *reinterpret_cast<uint4*>(&aT[2][srow][kl]) =
                make_uint4(l0.x, l0.y, l1.x, l1.y);
        }
        #pragma unroll
        for (int v = 0; v < 3; ++v)
            #pragma unroll
            for (int j = 0; j < 4; ++j)
                *reinterpret_cast<uint4*>(&bT[v][grow][gcol * 32 + j * 8]) = bq[v][j];
        __syncthreads();   // barrier 1: tiles visible

        // ---- issue next-chunk loads NOW: they fly during the MFMA phase,
        // and barrier-2's vmcnt(0) drain is covered by compute ----
        if (ch + 1 < NCHUNK) { LOAD_X(ch + 1); LOAD_B(ch + 1); }

        // ---- MFMA: this wave's K-half = 4 K=16 steps, 6 products each ----
        #pragma unroll
        for (int s = 0; s < 4; ++s) {
            const int ko = 16 * (4 * kh + s);
            bf16x8 ah = *reinterpret_cast<const bf16x8*>(aP[0] + ko);
            bf16x8 am = *reinterpret_cast<const bf16x8*>(aP[1] + ko);
            bf16x8 al = *reinterpret_cast<const bf16x8*>(aP[2] + ko);
            bf16x8 bh = *reinterpret_cast<const bf16x8*>(bP[0] + ko);
            bf16x8 bm = *reinterpret_cast<const bf16x8*>(bP[1] + ko);
            bf16x8 bl = *reinterpret_cast<const bf16x8*>(bP[2] + ko);
            acc = __builtin_amdgcn_mfma_f32_32x32x16_bf16(ah, bh, acc, 0, 0, 0);
            acc = __builtin_amdgcn_mfma_f32_32x32x16_bf16(ah, bm, acc, 0, 0, 0);
            acc = __builtin_amdgcn_mfma_f32_32x32x16_bf16(am, bh, acc, 0, 0, 0);
            acc = __builtin_amdgcn_mfma_f32_32x32x16_bf16(ah, bl, acc, 0, 0, 0);
            acc = __builtin_amdgcn_mfma_f32_32x32x16_bf16(am, bm, acc, 0, 0, 0);
            acc = __builtin_amdgcn_mfma_f32_32x32x16_bf16(al, bh, acc, 0, 0, 0);
        }
        __syncthreads();   // barrier 2: LDS reads done; drains loads (covered)
    }
#undef LOAD_X
#undef LOAD_B

    // ---- combine K-halves into score tile (sc_s aliases the staging pool;
    // all LDS reads completed before the last barrier). 32x32 C/D layout
    // (m74/m101): col = lane&31, row = (reg&3) + 8*(reg>>2) + 4*(lane>>5)
    const int e = 32 * wn + l31;
    if (kh == 0) {
        #pragma unroll
        for (int r = 0; r < 16; ++r) {
            const int t_loc = (r & 3) + 8 * (r >> 2) + 4 * lhi;
            sc_s[t_loc][e] = acc[r];
        }
    }
    __syncthreads();
    if (kh == 1) {
        #pragma unroll
        for (int r = 0; r < 16; ++r) {
            const int t_loc = (r & 3) + 8 * (r >> 2) + 4 * lhi;
            sc_s[t_loc][e] += acc[r] + bias_s[e];
        }
    }
    __syncthreads();

    // ---- pass 1: per-token top-2 (strict '>' keeps lowest index) ----
    if (tid < BTOK) {
        const int t = tid;
        float m1 = -INFINITY, m2 = -INFINITY;
        int   i1 = 0, i2 = 0;
        for (int ee = 0; ee < NEXP; ++ee) {
            const float s = sc_s[t][ee];
            if (s > m1)      { m2 = m1; i2 = i1; m1 = s; i1 = ee; }
            else if (s > m2) { m2 = s; i2 = ee; }
        }
        float z = 0.0f;
        for (int ee = 0; ee < NEXP; ++ee) z += __expf(sc_s[t][ee] - m1);

        const float e2  = expf(m2 - m1);
        const float inv = 1.0f / (1.0f + e2);
        const int   gt  = T0 + t;
        reinterpret_cast<float2*>(out_w)[gt]   = make_float2(inv, e2 * inv);
        reinterpret_cast<float2*>(out_idx)[gt] = make_float2((float)i1, (float)i2);
        m_s[t] = m1; zi_s[t] = 1.0f / z; i1_s[t] = i1; i2_s[t] = i2;
    }
    __syncthreads();

    // ---- pass 2: per-expert aux partials (per-block rows, no atomics) ----
    if (tid < NEXP) {
        const int ee = tid;
        float ps = 0.0f, gs = 0.0f;
        for (int t = 0; t < BTOK; ++t) {
            ps += __expf(sc_s[t][ee] - m_s[t]) * zi_s[t];
            gs += (float)((i1_s[t] == ee) + (i2_s[t] == ee));
        }
        prob_part[rt * NEXP + ee] = ps;
        gate_part[rt * NEXP + ee] = gs;
    }
}

// ===========================================================================
// Aux: sum per-block partials (prob/gate), form load-balancing loss.
// ===========================================================================
__global__ __launch_bounds__(256) void router_aux2(
    const float* __restrict__ prob_part,
    const float* __restrict__ gate_part,
    float* __restrict__ out_aux)
{
    __shared__ float rp[4][NEXP], rg[4][NEXP];
    const int e = threadIdx.x & 63;
    const int q = threadIdx.x >> 6;
    float sp = 0.0f, sg = 0.0f;
    for (int b = q * (NBLK / 4); b < (q + 1) * (NBLK / 4); ++b) {
        sp += prob_part[b * NEXP + e];
        sg += gate_part[b * NEXP + e];
    }
    rp[q][e] = sp; rg[q][e] = sg;
    __syncthreads();
    if (threadIdx.x < NEXP) {
        float pT = rp[0][e] + rp[1][e] + rp[2][e] + rp[3][e];
        float gT = rg[0][e] + rg[1][e] + rg[2][e] + rg[3][e];
        const float invT = 1.0f / (float)TTOT;
        float v = (gT * invT) * (pT * invT);
        #pragma unroll
        for (int off = 32; off > 0; off >>= 1)
            v += __shfl_down(v, off);
        if (e == 0) out_aux[0] = v * (float)NEXP;
    }
}

// ===========================================================================
// Fallback (round-1/3 proven): single fused fp32 kernel, if ws too small.
// ===========================================================================
#define BKF  32
#define LDAF (64 + 4)
__global__ __launch_bounds__(256) void router_main(
    const float* __restrict__ x,
    const float* __restrict__ gw,
    const float* __restrict__ rep,
    const float* __restrict__ loads,
    const float* __restrict__ counts,
    const int*   __restrict__ total_dec,
    float* __restrict__ out_w,
    float* __restrict__ out_idx,
    float* __restrict__ prob_acc,
    float* __restrict__ gate_acc)
{
    __shared__ float a_s[2][BKF][LDAF];
    __shared__ float b_s[2][BKF][LDAF];
    __shared__ float sc_s[64][LDS_SC];
    __shared__ float bias_s[NEXP];
    __shared__ float m_s[64], z_s[64];
    __shared__ int   i1_s[64], i2_s[64];

    const int tid = threadIdx.x;
    const int tx  = tid & 15;
    const int ty  = tid >> 4;
    const int r0  = tid >> 3;
    const int c4  = tid & 7;
    const int t0  = blockIdx.x * 64;

    if (tid < NEXP) {
        float L = logf((float)(*total_dec) + 1.0f);
        bias_s[tid] = 0.1f * rep[tid] - 0.1f * loads[tid]
                    + 0.1f * sqrtf(L / (counts[tid] + 1e-10f));
    }

    const float4* __restrict__ x4 = reinterpret_cast<const float4*>(x) + (size_t)t0 * H4;
    const float4* __restrict__ g4 = reinterpret_cast<const float4*>(gw);

    float acc[4][4] = {};

#define STORE_TILE(BUFI, A0, A1, B0, B1) do {                                  \
        float _t0[4] = {(A0).x, (A0).y, (A0).z, (A0).w};                       \
        float _t1[4] = {(A1).x, (A1).y, (A1).z, (A1).w};                       \
        float _t2[4] = {(B0).x, (B0).y, (B0).z, (B0).w};                       \
        float _t3[4] = {(B1).x, (B1).y, (B1).z, (B1).w};                       \
        _Pragma("unroll")                                                      \
        for (int u = 0; u < 4; ++u) {                                          \
            a_s[BUFI][c4 * 4 + u][r0]      = _t0[u];                           \
            a_s[BUFI][c4 * 4 + u][r0 + 32] = _t1[u];                           \
            b_s[BUFI][c4 * 4 + u][r0]      = _t2[u];                           \
            b_s[BUFI][c4 * 4 + u][r0 + 32] = _t3[u];                           \
        } } while (0)

    {
        float4 a0 = x4[(size_t)r0 * H4 + c4];
        float4 a1 = x4[(size_t)(r0 + 32) * H4 + c4];
        float4 b0 = g4[(size_t)r0 * H4 + c4];
        float4 b1 = g4[(size_t)(r0 + 32) * H4 + c4];
        STORE_TILE(0, a0, a1, b0, b1);
    }
    __syncthreads();

    int buf = 0;
    for (int it = 0; it < HDIM / BKF; ++it) {
        float4 na0, na1, nb0, nb1;
        const bool has_next = (it + 1 < HDIM / BKF);
        if (has_next) {
            const int k4 = (it + 1) * (BKF / 4);
            na0 = x4[(size_t)r0 * H4 + k4 + c4];
            na1 = x4[(size_t)(r0 + 32) * H4 + k4 + c4];
            nb0 = g4[(size_t)r0 * H4 + k4 + c4];
            nb1 = g4[(size_t)(r0 + 32) * H4 + k4 + c4];
        }
        #pragma unroll
        for (int kk = 0; kk < BKF; ++kk) {
            const float4 afv = *reinterpret_cast<const float4*>(&a_s[buf][kk][ty * 4]);
            const float4 bfv = *reinterpret_cast<const float4*>(&b_s[buf][kk][tx * 4]);
            const float af[4] = {afv.x, afv.y, afv.z, afv.w};
            const float bf[4] = {bfv.x, bfv.y, bfv.z, bfv.w};
            #pragma unroll
            for (int i = 0; i < 4; ++i)
                #pragma unroll
                for (int j = 0; j < 4; ++j)
                    acc[i][j] = fmaf(af[i], bf[j], acc[i][j]);
        }
        if (has_next) STORE_TILE(buf ^ 1, na0, na1, nb0, nb1);
        __syncthreads();
        buf ^= 1;
    }
#undef STORE_TILE

    #pragma unroll
    for (int i = 0; i < 4; ++i)
        #pragma unroll
        for (int j = 0; j < 4; ++j)
            sc_s[ty * 4 + i][tx * 4 + j] = acc[i][j] + bias_s[tx * 4 + j];
    __syncthreads();

    if (tid < 64) {
        const int t = tid;
        float m1 = -INFINITY, m2 = -INFINITY;
        int   i1 = 0, i2 = 0;
        for (int e = 0; e < NEXP; ++e) {
            const float s = sc_s[t][e];
            if (s > m1)      { m2 = m1; i2 = i1; m1 = s; i1 = e; }
            else if (s > m2) { m2 = s; i2 = e; }
        }
        float z = 0.0f;
        for (int e = 0; e < NEXP; ++e) z += expf(sc_s[t][e] - m1);
        const float e2  = expf(m2 - m1);
        const float inv = 1.0f / (1.0f + e2);
        const int   gt  = t0 + t;
        reinterpret_cast<float2*>(out_w)[gt]   = make_float2(inv, e2 * inv);
        reinterpret_cast<float2*>(out_idx)[gt] = make_float2((float)i1, (float)i2);
        m_s[t] = m1; z_s[t] = z; i1_s[t] = i1; i2_s[t] = i2;
    }
    __syncthreads();

    if (tid < NEXP) {
        const int e = tid;
        float ps = 0.0f, gs = 0.0f;
        for (int t = 0; t < 64; ++t) {
            ps += expf(sc_s[t][e] - m_s[t]) / z_s[t];
            gs += (float)((i1_s[t] == e) + (i2_s[t] == e));
        }
        atomicAdd(&prob_acc[e], ps);
        atomicAdd(&gate_acc[e], gs);
    }
}

__global__ void router_aux(const float* __restrict__ prob_acc,
                           const float* __restrict__ gate_acc,
                           float* __restrict__ out_aux)
{
    const float invT = 1.0f / (float)TTOT;
    const int e = threadIdx.x;
    float v = (gate_acc[e] * invT) * (prob_acc[e] * invT);
    #pragma unroll
    for (int off = 32; off > 0; off >>= 1)
        v += __shfl_down(v, off);
    if (e == 0) out_aux[0] = v * (float)NEXP;
}

extern "C" void kernel_launch(void* const* d_in, const int* in_sizes, int n_in,
                              void* d_out, int out_size, void* d_ws, size_t ws_size,
                              hipStream_t stream)
{
    const float* x      = (const float*)d_in[0];
    const float* gw     = (const float*)d_in[1];
    const float* rep    = (const float*)d_in[2];
    const float* loads  = (const float*)d_in[3];
    const float* counts = (const float*)d_in[4];
    const int*   total  = (const int*)d_in[5];

    float* out     = (float*)d_out;
    float* out_w   = out;            // [16384*2] routing weights
    float* out_idx = out + 32768;    // [16384*2] expert indices as float
    float* out_aux = out + 65536;    // [1] aux loss

    if (ws_size >= (size_t)WS_NEEDED_FLOATS * sizeof(float)) {
        float* prob_part = (float*)d_ws;
        float* gate_part = prob_part + NBLK * NEXP;
        u16*   gws       = (u16*)((float*)d_ws + WS_GWS_OFF);

        split_gw_k<<<dim3(NEXP * HDIM / 4 / 256), dim3(256), 0, stream>>>(gw, gws);
        router_fused3<<<dim3(NBLK), dim3(256), 0, stream>>>(
            x, gws, rep, loads, counts, total, out_w, out_idx, prob_part, gate_part);
        router_aux2<<<dim3(1), dim3(256), 0, stream>>>(prob_part, gate_part, out_aux);
    } else {
        float* prob_acc = (float*)d_ws;
        float* gate_acc = prob_acc + NEXP;
        (void)hipMemsetAsync(d_ws, 0, 2 * NEXP * sizeof(float), stream);
        router_main<<<dim3(TTOT / 64), dim3(256), 0, stream>>>(
            x, gw, rep, loads, counts, total, out_w, out_idx, prob_acc, gate_acc);
        router_aux<<<dim3(1), dim3(64), 0, stream>>>(prob_acc, gate_acc, out_aux);
    }
}

// Round 9
// 228.282 us; speedup vs baseline: 1.3997x; 1.3997x over previous
//
#include <hip/hip_runtime.h>
#include <cmath>

#define HDIM 2048
#define H4   (HDIM / 4)         // 512 float4 per row
#define NEXP 64
#define TTOT 16384
#define KSPLIT 2
#define KBLK (HDIM / KSPLIT)    // 1024 k per block
#define BKC  64                 // k per staged chunk
#define NCHUNK (KBLK / BKC)     // 16
#define BTOK 64                 // tokens per block
#define LDT  72                 // padded k-stride (shorts); rows 16B-aligned
#define LDS_SC 65

// ws layout: [0..63] prob_acc, [64..127] gate_acc, [128..] partials
#define WS_PARTIAL_OFF 128
#define PARTIAL_FLOATS ((size_t)(TTOT / BTOK) * KSPLIT * BTOK * NEXP)  // 2.1M

typedef short  bf16x8 __attribute__((ext_vector_type(8)));
typedef float  f32x16 __attribute__((ext_vector_type(16)));

// round-to-nearest-even fp32 -> bf16 (bits, low16 zero); returns rounded value
// as fp32 so the residual (exact, Sterbenz) can be computed.
__device__ __forceinline__ unsigned bf_rn_u(float f, float* back) {
    unsigned u = __float_as_uint(f);
    unsigned r = (u + 0x7fffu + ((u >> 16) & 1u)) & 0xffff0000u;
    *back = __uint_as_float(r);
    return r;
}

// ===========================================================================
// Kernel 1: MFMA GEMM, exact 3-way bf16 split of fp32 (x = h+m+l (+~2^-23)).
// scores = hH + hM + mH + hL + mM + lH.
// Block: 64 tokens x 64 experts x K=1024 (grid 256 x 2). 4 waves, each wave
// ONE 32x32 tile via mfma_f32_32x32x16_bf16 (24 MFMA/chunk vs 48 with 16x16).
// Split: RNE for h,m; round-half-up for l; v_perm packing. fp32 partials.
// [R8 restore: this exact kernel measured 228.865 us in round 1 -- best of
//  9 rounds. All structural departures (fusion, KSPLIT=4, BKC=128) regressed.]
// ===========================================================================
__global__ __launch_bounds__(256, 2) void router_gemm_mfma(
    const float* __restrict__ x,        // [T, H]
    const float* __restrict__ gw,       // [E, H]  (= B^T layout, E x K)
    float* __restrict__ partial,        // [256][2][64*64]
    float* __restrict__ accs)           // [128] prob/gate accumulators
{
    __shared__ short aT[3][BTOK][LDT];  // x  tile: h/m/l variants, [token][k]
    __shared__ short bT[3][NEXP][LDT];  // gw tile: h/m/l variants, [expert][k]

    const int tid  = threadIdx.x;
    const int lane = tid & 63;
    const int l31  = lane & 31;
    const int lhi  = lane >> 5;         // K-half within fragment
    const int w    = tid >> 6;          // wave 0..3
    const int wm   = w & 1;             // token half  (32 rows)
    const int wn   = w >> 1;            // expert half (32 cols)
    const int tb   = blockIdx.x;        // token block 0..255
    const int kg   = blockIdx.y;        // K half 0..1
    const int T0   = tb * BTOK;

    // zero the aux accumulators here (replaces the hipMemsetAsync dispatch);
    // gemm grid completes before router_reduce launches (stream order).
    if (tb == 0 && kg == 0 && tid < 2 * NEXP) accs[tid] = 0.0f;

    // staging role: thread t handles row t>>2, float4 cols (t&3)+4j, j=0..3
    const int srow = tid >> 2;
    const int scol = tid & 3;

    const float4* __restrict__ x4 = reinterpret_cast<const float4*>(x)
        + (size_t)(T0 + srow) * H4 + (size_t)kg * (H4 / 2) + scol;
    const float4* __restrict__ g4 = reinterpret_cast<const float4*>(gw)
        + (size_t)srow * H4 + (size_t)kg * (H4 / 2) + scol;

    f32x16 acc;
    #pragma unroll
    for (int i = 0; i < 16; ++i) acc[i] = 0.0f;

    // fragment read pointers (chunk-invariant); rows 16B-aligned (LDT=72)
    const short* aP[3];
    const short* bP[3];
    #pragma unroll
    for (int v = 0; v < 3; ++v) {
        aP[v] = &aT[v][32 * wm + l31][8 * lhi];
        bP[v] = &bT[v][32 * wn + l31][8 * lhi];
    }

    float4 xa[4], xb[4];   // prefetched fp32 chunk data (consumed before reload)

#define LOAD_CHUNK(CH) do {                                                    \
        _Pragma("unroll")                                                      \
        for (int j = 0; j < 4; ++j) {                                          \
            xa[j] = x4[(CH) * (BKC / 4) + 4 * j];                              \
            xb[j] = g4[(CH) * (BKC / 4) + 4 * j];                              \
        } } while (0)

    // split one float4 into h/m/l bf16 short4s and store to tile at [ROW][kl].
    // h,m: RNE (residuals exact via Sterbenz). l: round-half-up (+0x8000),
    // no float-back needed. Packing: v_perm grabs the two top16s in one op.
#define SPLIT_STORE(TILE, ROW, FV, JJ) do {                                    \
        const float _f[4] = {(FV).x, (FV).y, (FV).z, (FV).w};                  \
        unsigned _h[4], _m[4], _l[4];                                          \
        _Pragma("unroll")                                                      \
        for (int u = 0; u < 4; ++u) {                                          \
            float _b0, _b1;                                                    \
            _h[u] = bf_rn_u(_f[u], &_b0);                                      \
            const float _r1 = _f[u] - _b0;                                     \
            _m[u] = bf_rn_u(_r1, &_b1);                                        \
            const float _r2 = _r1 - _b1;                                       \
            _l[u] = __float_as_uint(_r2) + 0x8000u;                            \
        }                                                                      \
        const int _kl = 4 * (scol + 4 * (JJ));                                 \
        *reinterpret_cast<uint2*>(&TILE[0][ROW][_kl]) =                        \
            make_uint2(__builtin_amdgcn_perm(_h[1], _h[0], 0x07060302u),       \
                       __builtin_amdgcn_perm(_h[3], _h[2], 0x07060302u));      \
        *reinterpret_cast<uint2*>(&TILE[1][ROW][_kl]) =                        \
            make_uint2(__builtin_amdgcn_perm(_m[1], _m[0], 0x07060302u),       \
                       __builtin_amdgcn_perm(_m[3], _m[2], 0x07060302u));      \
        *reinterpret_cast<uint2*>(&TILE[2][ROW][_kl]) =                        \
            make_uint2(__builtin_amdgcn_perm(_l[1], _l[0], 0x07060302u),       \
                       __builtin_amdgcn_perm(_l[3], _l[2], 0x07060302u));      \
    } while (0)

    LOAD_CHUNK(0);

    for (int ch = 0; ch < NCHUNK; ++ch) {
        // ---- convert prefetched regs -> LDS (regs free after this) ----
        #pragma unroll
        for (int j = 0; j < 4; ++j) {
            SPLIT_STORE(aT, srow, xa[j], j);
            SPLIT_STORE(bT, srow, xb[j], j);
        }
        __syncthreads();

        if (ch + 1 < NCHUNK) LOAD_CHUNK(ch + 1);   // overlaps MFMA below

        // ---- MFMA over this chunk: 4 K=16 steps, 6 products each ----
        #pragma unroll
        for (int ks = 0; ks < 4; ++ks) {
            bf16x8 ah = *reinterpret_cast<const bf16x8*>(aP[0] + 16 * ks);
            bf16x8 am = *reinterpret_cast<const bf16x8*>(aP[1] + 16 * ks);
            bf16x8 al = *reinterpret_cast<const bf16x8*>(aP[2] + 16 * ks);
            bf16x8 bh = *reinterpret_cast<const bf16x8*>(bP[0] + 16 * ks);
            bf16x8 bm = *reinterpret_cast<const bf16x8*>(bP[1] + 16 * ks);
            bf16x8 bl = *reinterpret_cast<const bf16x8*>(bP[2] + 16 * ks);
            acc = __builtin_amdgcn_mfma_f32_32x32x16_bf16(ah, bh, acc, 0, 0, 0);
            acc = __builtin_amdgcn_mfma_f32_32x32x16_bf16(ah, bm, acc, 0, 0, 0);
            acc = __builtin_amdgcn_mfma_f32_32x32x16_bf16(am, bh, acc, 0, 0, 0);
            acc = __builtin_amdgcn_mfma_f32_32x32x16_bf16(ah, bl, acc, 0, 0, 0);
            acc = __builtin_amdgcn_mfma_f32_32x32x16_bf16(am, bm, acc, 0, 0, 0);
            acc = __builtin_amdgcn_mfma_f32_32x32x16_bf16(al, bh, acc, 0, 0, 0);
        }
        __syncthreads();   // LDS free for next chunk's staging
    }
#undef LOAD_CHUNK
#undef SPLIT_STORE

    // ---- write fp32 partials. 32x32 C/D layout (m74/m101):
    // col = lane&31, row = (reg&3) + 8*(reg>>2) + 4*(lane>>5)
    float* pbase = partial + ((size_t)tb * KSPLIT + kg) * (BTOK * NEXP);
    const int e = 32 * wn + l31;
    #pragma unroll
    for (int r = 0; r < 16; ++r) {
        const int t_loc = 32 * wm + (r & 3) + 8 * (r >> 2) + 4 * lhi;
        pbase[(size_t)t_loc * NEXP + e] = acc[r];
    }
}

// ===========================================================================
// Kernel 2: sum 2 K-split partials + bias, top-2 + softmax + aux partials.
// __expf for the aux-only z/ps loops; libm expf kept for output weights.
// ===========================================================================
__global__ __launch_bounds__(256) void router_reduce(
    const float* __restrict__ partial,
    const float* __restrict__ rep,
    const float* __restrict__ loads,
    const float* __restrict__ counts,
    const int*   __restrict__ total_dec,
    float* __restrict__ out_w,
    float* __restrict__ out_idx,
    float* __restrict__ prob_acc,
    float* __restrict__ gate_acc)
{
    __shared__ float sc_s[BTOK][LDS_SC];
    __shared__ float bias_s[NEXP];
    __shared__ float m_s[BTOK], zi_s[BTOK];
    __shared__ int   i1_s[BTOK], i2_s[BTOK];

    const int tid = threadIdx.x;
    const int rt  = blockIdx.x;        // 64-token tile 0..255
    const int t0  = rt * BTOK;

    if (tid < NEXP) {
        float L = logf((float)(*total_dec) + 1.0f);
        bias_s[tid] = 0.1f * rep[tid] - 0.1f * loads[tid]
                    + 0.1f * sqrtf(L / (counts[tid] + 1e-10f));
    }
    __syncthreads();

    const float* p = partial + (size_t)rt * KSPLIT * (BTOK * NEXP);
    #pragma unroll
    for (int o = 0; o < (BTOK * NEXP) / 256; ++o) {
        const int idx = o * 256 + tid;
        float s = p[idx] + p[BTOK * NEXP + idx];
        sc_s[idx >> 6][idx & 63] = s + bias_s[idx & 63];
    }
    __syncthreads();

    // pass 1: per-token top-2 (strict '>' keeps lowest index), softmax weights
    if (tid < BTOK) {
        const int t = tid;
        float m1 = -INFINITY, m2 = -INFINITY;
        int   i1 = 0, i2 = 0;
        for (int e = 0; e < NEXP; ++e) {
            const float s = sc_s[t][e];
            if (s > m1)      { m2 = m1; i2 = i1; m1 = s; i1 = e; }
            else if (s > m2) { m2 = s; i2 = e; }
        }
        float z = 0.0f;
        for (int e = 0; e < NEXP; ++e) z += __expf(sc_s[t][e] - m1);

        const float e2  = expf(m2 - m1);
        const float inv = 1.0f / (1.0f + e2);
        const int   gt  = t0 + t;
        reinterpret_cast<float2*>(out_w)[gt]   = make_float2(inv, e2 * inv);
        reinterpret_cast<float2*>(out_idx)[gt] = make_float2((float)i1, (float)i2);
        m_s[t] = m1; zi_s[t] = 1.0f / z; i1_s[t] = i1; i2_s[t] = i2;
    }
    __syncthreads();

    // pass 2: per-expert partial sums for aux loss
    if (tid < NEXP) {
        const int e = tid;
        float ps = 0.0f, gs = 0.0f;
        for (int t = 0; t < BTOK; ++t) {
            ps += __expf(sc_s[t][e] - m_s[t]) * zi_s[t];
            gs += (float)((i1_s[t] == e) + (i2_s[t] == e));
        }
        atomicAdd(&prob_acc[e], ps);
        atomicAdd(&gate_acc[e], gs);
    }
}

// ===========================================================================
// Fallback (round-1/3 proven): single fused fp32 kernel, if ws too small.
// ===========================================================================
#define BKF  32
#define LDAF (64 + 4)
__global__ __launch_bounds__(256) void router_main(
    const float* __restrict__ x,
    const float* __restrict__ gw,
    const float* __restrict__ rep,
    const float* __restrict__ loads,
    const float* __restrict__ counts,
    const int*   __restrict__ total_dec,
    float* __restrict__ out_w,
    float* __restrict__ out_idx,
    float* __restrict__ prob_acc,
    float* __restrict__ gate_acc)
{
    __shared__ float a_s[2][BKF][LDAF];
    __shared__ float b_s[2][BKF][LDAF];
    __shared__ float sc_s[64][LDS_SC];
    __shared__ float bias_s[NEXP];
    __shared__ float m_s[64], z_s[64];
    __shared__ int   i1_s[64], i2_s[64];

    const int tid = threadIdx.x;
    const int tx  = tid & 15;
    const int ty  = tid >> 4;
    const int r0  = tid >> 3;
    const int c4  = tid & 7;
    const int t0  = blockIdx.x * 64;

    if (tid < NEXP) {
        float L = logf((float)(*total_dec) + 1.0f);
        bias_s[tid] = 0.1f * rep[tid] - 0.1f * loads[tid]
                    + 0.1f * sqrtf(L / (counts[tid] + 1e-10f));
    }

    const float4* __restrict__ x4 = reinterpret_cast<const float4*>(x) + (size_t)t0 * H4;
    const float4* __restrict__ g4 = reinterpret_cast<const float4*>(gw);

    float acc[4][4] = {};

#define STORE_TILE(BUFI, A0, A1, B0, B1) do {                                  \
        float _t0[4] = {(A0).x, (A0).y, (A0).z, (A0).w};                       \
        float _t1[4] = {(A1).x, (A1).y, (A1).z, (A1).w};                       \
        float _t2[4] = {(B0).x, (B0).y, (B0).z, (B0).w};                       \
        float _t3[4] = {(B1).x, (B1).y, (B1).z, (B1).w};                       \
        _Pragma("unroll")                                                      \
        for (int u = 0; u < 4; ++u) {                                          \
            a_s[BUFI][c4 * 4 + u][r0]      = _t0[u];                           \
            a_s[BUFI][c4 * 4 + u][r0 + 32] = _t1[u];                           \
            b_s[BUFI][c4 * 4 + u][r0]      = _t2[u];                           \
            b_s[BUFI][c4 * 4 + u][r0 + 32] = _t3[u];                           \
        } } while (0)

    {
        float4 a0 = x4[(size_t)r0 * H4 + c4];
        float4 a1 = x4[(size_t)(r0 + 32) * H4 + c4];
        float4 b0 = g4[(size_t)r0 * H4 + c4];
        float4 b1 = g4[(size_t)(r0 + 32) * H4 + c4];
        STORE_TILE(0, a0, a1, b0, b1);
    }
    __syncthreads();

    int buf = 0;
    for (int it = 0; it < HDIM / BKF; ++it) {
        float4 na0, na1, nb0, nb1;
        const bool has_next = (it + 1 < HDIM / BKF);
        if (has_next) {
            const int k4 = (it + 1) * (BKF / 4);
            na0 = x4[(size_t)r0 * H4 + k4 + c4];
            na1 = x4[(size_t)(r0 + 32) * H4 + k4 + c4];
            nb0 = g4[(size_t)r0 * H4 + k4 + c4];
            nb1 = g4[(size_t)(r0 + 32) * H4 + k4 + c4];
        }
        #pragma unroll
        for (int kk = 0; kk < BKF; ++kk) {
            const float4 afv = *reinterpret_cast<const float4*>(&a_s[buf][kk][ty * 4]);
            const float4 bfv = *reinterpret_cast<const float4*>(&b_s[buf][kk][tx * 4]);
            const float af[4] = {afv.x, afv.y, afv.z, afv.w};
            const float bf[4] = {bfv.x, bfv.y, bfv.z, bfv.w};
            #pragma unroll
            for (int i = 0; i < 4; ++i)
                #pragma unroll
                for (int j = 0; j < 4; ++j)
                    acc[i][j] = fmaf(af[i], bf[j], acc[i][j]);
        }
        if (has_next) STORE_TILE(buf ^ 1, na0, na1, nb0, nb1);
        __syncthreads();
        buf ^= 1;
    }
#undef STORE_TILE

    #pragma unroll
    for (int i = 0; i < 4; ++i)
        #pragma unroll
        for (int j = 0; j < 4; ++j)
            sc_s[ty * 4 + i][tx * 4 + j] = acc[i][j] + bias_s[tx * 4 + j];
    __syncthreads();

    if (tid < 64) {
        const int t = tid;
        float m1 = -INFINITY, m2 = -INFINITY;
        int   i1 = 0, i2 = 0;
        for (int e = 0; e < NEXP; ++e) {
            const float s = sc_s[t][e];
            if (s > m1)      { m2 = m1; i2 = i1; m1 = s; i1 = e; }
            else if (s > m2) { m2 = s; i2 = e; }
        }
        float z = 0.0f;
        for (int e = 0; e < NEXP; ++e) z += expf(sc_s[t][e] - m1);
        const float e2  = expf(m2 - m1);
        const float inv = 1.0f / (1.0f + e2);
        const int   gt  = t0 + t;
        reinterpret_cast<float2*>(out_w)[gt]   = make_float2(inv, e2 * inv);
        reinterpret_cast<float2*>(out_idx)[gt] = make_float2((float)i1, (float)i2);
        m_s[t] = m1; z_s[t] = z; i1_s[t] = i1; i2_s[t] = i2;
    }
    __syncthreads();

    if (tid < NEXP) {
        const int e = tid;
        float ps = 0.0f, gs = 0.0f;
        for (int t = 0; t < 64; ++t) {
            ps += expf(sc_s[t][e] - m_s[t]) / z_s[t];
            gs += (float)((i1_s[t] == e) + (i2_s[t] == e));
        }
        atomicAdd(&prob_acc[e], ps);
        atomicAdd(&gate_acc[e], gs);
    }
}

__global__ void router_aux(const float* __restrict__ prob_acc,
                           const float* __restrict__ gate_acc,
                           float* __restrict__ out_aux)
{
    const float invT = 1.0f / (float)TTOT;
    const int e = threadIdx.x;
    float v = (gate_acc[e] * invT) * (prob_acc[e] * invT);
    #pragma unroll
    for (int off = 32; off > 0; off >>= 1)
        v += __shfl_down(v, off);
    if (e == 0) out_aux[0] = v * (float)NEXP;
}

extern "C" void kernel_launch(void* const* d_in, const int* in_sizes, int n_in,
                              void* d_out, int out_size, void* d_ws, size_t ws_size,
                              hipStream_t stream)
{
    const float* x      = (const float*)d_in[0];
    const float* gw     = (const float*)d_in[1];
    const float* rep    = (const float*)d_in[2];
    const float* loads  = (const float*)d_in[3];
    const float* counts = (const float*)d_in[4];
    const int*   total  = (const int*)d_in[5];

    float* out     = (float*)d_out;
    float* out_w   = out;            // [16384*2] routing weights
    float* out_idx = out + 32768;    // [16384*2] expert indices as float
    float* out_aux = out + 65536;    // [1] aux loss

    float* prob_acc = (float*)d_ws;
    float* gate_acc = prob_acc + NEXP;
    float* partial  = (float*)d_ws + WS_PARTIAL_OFF;

    const size_t ws_needed = (WS_PARTIAL_OFF + PARTIAL_FLOATS) * sizeof(float);

    if (ws_size >= ws_needed) {
        // accumulator zeroing is folded into router_gemm_mfma block (0,0)
        router_gemm_mfma<<<dim3(TTOT / BTOK, KSPLIT), dim3(256), 0, stream>>>(
            x, gw, partial, prob_acc);
        router_reduce<<<dim3(TTOT / BTOK), dim3(256), 0, stream>>>(
            partial, rep, loads, counts, total, out_w, out_idx, prob_acc, gate_acc);
    } else {
        (void)hipMemsetAsync(d_ws, 0, 2 * NEXP * sizeof(float), stream);
        router_main<<<dim3(TTOT / 64), dim3(256), 0, stream>>>(
            x, gw, rep, loads, counts, total, out_w, out_idx, prob_acc, gate_acc);
    }
    router_aux<<<dim3(1), dim3(64), 0, stream>>>(prob_acc, gate_acc, out_aux);
}